// Round 2
// baseline (73.835 us; speedup 1.0000x reference)
//
#include <hip/hip_runtime.h>

// out[n,m] = -sum_d |x[n,d]-y[m,d]|  N=M=2048, D=128, fp32.
// VALU-bound (2 ops/elem). Strategy: NO LDS, NO barriers.
//  - lane l of a wave owns column m = mgroup*64+l; y[m,0:128] lives in
//    128 VGPRs for the wave's whole life (32x float4, statically indexed).
//  - x[n,:] is wave-uniform -> scalar loads (SMEM pipe, parallel to VALU).
//  - inner loop: v_sub_f32 (sgpr operand) + v_add_f32 acc, acc, abs(tmp).
//    4 independent acc chains (float4 components) hide the 4-cyc add latency.
// Decomposition: wave = 64 cols x 32 rows -> 2048 waves = 512 blocks(256thr)
// = exactly 2 blocks/CU, 8 waves/CU, no tail.

#define DD 128
#define ROWS_PER_WAVE 32

__launch_bounds__(256, 2)
__global__ void l1_dist_kernel(const float* __restrict__ X,
                               const float* __restrict__ Y,
                               float* __restrict__ out,
                               int N, int M) {
    const int wave = threadIdx.x >> 6;
    const int lane = threadIdx.x & 63;
    const int gw = blockIdx.x * 4 + wave;   // global wave id, 0..2047
    const int mgroup = gw & 31;             // 32 column-groups
    const int rgroup = gw >> 5;             // 64 row-groups
    const int m = mgroup * 64 + lane;
    const int n0 = rgroup * ROWS_PER_WAVE;

    // Pull this lane's column into registers: y[m, 0:128] = 32 x float4.
    // Stride between lanes is 512B (uncoalesced) but it's a one-time, L2-hit
    // prologue (inputs are 2 MB total).
    float4 yr[32];
    const float4* yp = (const float4*)(Y + (size_t)m * DD);
#pragma unroll
    for (int j = 0; j < 32; ++j) yr[j] = yp[j];

    for (int i = 0; i < ROWS_PER_WAVE; ++i) {
        const int n = n0 + i;
        const float4* xp = (const float4*)(X + (size_t)n * DD);  // uniform
        float ax = 0.f, ay = 0.f, az = 0.f, aw = 0.f;
#pragma unroll
        for (int j = 0; j < 32; ++j) {
            float4 xv = xp[j];   // wave-uniform -> s_load (scalar pipe)
            ax += __builtin_fabsf(xv.x - yr[j].x);
            ay += __builtin_fabsf(xv.y - yr[j].y);
            az += __builtin_fabsf(xv.z - yr[j].z);
            aw += __builtin_fabsf(xv.w - yr[j].w);
        }
        // coalesced 256B wave-store
        out[(size_t)n * M + m] = -((ax + ay) + (az + aw));
    }
}

extern "C" void kernel_launch(void* const* d_in, const int* in_sizes, int n_in,
                              void* d_out, int out_size, void* d_ws, size_t ws_size,
                              hipStream_t stream) {
    const float* x = (const float*)d_in[0];
    const float* y = (const float*)d_in[1];
    float* out = (float*)d_out;
    const int D = DD;
    const int N = in_sizes[0] / D;   // 2048
    const int M = in_sizes[1] / D;   // 2048
    const int waves = (N / ROWS_PER_WAVE) * (M / 64); // 2048
    dim3 grid(waves / 4);            // 4 waves (256 thr) per block -> 512
    l1_dist_kernel<<<grid, 256, 0, stream>>>(x, y, out, N, M);
}

// Round 3
// 55.182 us; speedup vs baseline: 1.3380x; 1.3380x over previous
//
#include <hip/hip_runtime.h>

// out[n,m] = -sum_d |x[n,d]-y[m,d]|  N=M=2048, D=128, fp32.  VALU-bound.
// Lane owns column m: y[m,0:128] resident in 128 VGPRs.
// x rows are wave-uniform -> forced onto the SCALAR pipe:
//   - wave id via readfirstlane (provably uniform for divergence analysis)
//   - x pointer cast to address_space(4) (constant) -> s_load_dwordx16
// Inner loop: v_sub_f32 (sgpr src0) + v_add_f32 acc, acc, abs(tmp).
// 4 independent chains per row. No LDS, no barriers, no acc arrays.

typedef float f4 __attribute__((ext_vector_type(4)));
typedef __attribute__((address_space(4))) const f4 cf4;

#define DD 128
#define ROWS 16   // rows per wave -> 4096 waves = 1024 blocks = 4 blocks/CU

__launch_bounds__(256)
__global__ void l1_dist_kernel(const float* __restrict__ X,
                               const float* __restrict__ Y,
                               float* __restrict__ out,
                               int N, int M) {
    // readfirstlane makes the wave id (and thus x addresses) uniform to the
    // compiler, enabling s_load for the constant-AS x pointer.
    const int wave = __builtin_amdgcn_readfirstlane((int)(threadIdx.x >> 6));
    const int lane = threadIdx.x & 63;
    const int gw = blockIdx.x * 4 + wave;   // 0..4095
    const int mg = gw & 31;                 // 32 column groups
    const int rg = gw >> 5;                 // 128 row groups
    const int m  = mg * 64 + lane;
    const int n0 = rg * ROWS;

    // Lane-resident y column: 32 x float4 = 128 VGPRs. One-time L2-hit load.
    f4 yv[32];
    const f4* yp = (const f4*)(Y + (size_t)m * DD);
#pragma unroll
    for (int j = 0; j < 32; ++j) yv[j] = yp[j];

#pragma unroll 2
    for (int r = 0; r < ROWS; ++r) {
        cf4* xp = (cf4*)(X + (size_t)(n0 + r) * DD);   // uniform, constant AS
        float a0 = 0.f, a1 = 0.f, a2 = 0.f, a3 = 0.f;
#pragma unroll
        for (int j = 0; j < 32; ++j) {
            f4 xv = xp[j];   // s_load: scalar pipe, data lands in SGPRs
            a0 += __builtin_fabsf(xv.x - yv[j].x);
            a1 += __builtin_fabsf(xv.y - yv[j].y);
            a2 += __builtin_fabsf(xv.z - yv[j].z);
            a3 += __builtin_fabsf(xv.w - yv[j].w);
        }
        out[(size_t)(n0 + r) * M + m] = -((a0 + a1) + (a2 + a3));
    }
}

extern "C" void kernel_launch(void* const* d_in, const int* in_sizes, int n_in,
                              void* d_out, int out_size, void* d_ws, size_t ws_size,
                              hipStream_t stream) {
    const float* x = (const float*)d_in[0];
    const float* y = (const float*)d_in[1];
    float* out = (float*)d_out;
    const int D = DD;
    const int N = in_sizes[0] / D;   // 2048
    const int M = in_sizes[1] / D;   // 2048
    const int waves = (M / 64) * (N / ROWS);  // 4096
    dim3 grid(waves / 4);                     // 1024 blocks of 256 threads
    l1_dist_kernel<<<grid, 256, 0, stream>>>(x, y, out, N, M);
}

// Round 4
// 45.171 us; speedup vs baseline: 1.6346x; 1.2216x over previous
//
#include <hip/hip_runtime.h>

// out[n,m] = -sum_d |x[n,d]-y[m,d]|  N=M=2048, D=128, fp32.  VALU-bound.
// R0 structure was right; its deficit was occupancy (256 blocks = 1/CU).
// Now: 64x128 tile per 512-thread block -> 512 blocks = 2 blocks/CU
// = 4 waves/SIMD; two independent blocks/CU mask each other's barriers.
// DK=64 (2 chunks, 4 barriers total). XOR-swizzled LDS (16B granule):
//   y-reads: 16 distinct 16B slots / 256B span -> 2 lanes/bank (free)
//   x-reads: 4 distinct addresses, 16-way broadcast (1 bank cycle)
//   staged writes: exactly minimum bank cycles.
// Inner dq-step: 10 ds_read_b128 vs 128 VALU instr -> VALU-bound.

#define DD 128
#define BROWS 64
#define BCOLS 128
#define DK 64
#define TM 2
#define TN 8

__launch_bounds__(512, 4)   // 4 waves/EU -> 2 blocks(512thr)/CU
__global__ void l1_dist_kernel(const float* __restrict__ X,
                               const float* __restrict__ Y,
                               float* __restrict__ out,
                               int N, int M) {
    __shared__ float xs[BROWS * DK];   // 16 KB, swizzled
    __shared__ float ys[BCOLS * DK];   // 32 KB, swizzled

    const int tid = threadIdx.x;
    const int tx = tid & 15;           // col group 0..15
    const int ty = tid >> 4;           // row group 0..31
    const int brow = blockIdx.y * BROWS;
    const int bcol = blockIdx.x * BCOLS;

    float acc[TM][TN];
#pragma unroll
    for (int i = 0; i < TM; ++i)
#pragma unroll
        for (int j = 0; j < TN; ++j) acc[i][j] = 0.f;

    for (int d0 = 0; d0 < DD; d0 += DK) {
        __syncthreads();
        // stage xs: 64 rows x 16 quads = 1024 f4; 512 threads -> 2 each
#pragma unroll
        for (int k = 0; k < 2; ++k) {
            int idx = tid + k * 512;
            int r = idx >> 4, q = idx & 15;
            float4 v = *(const float4*)&X[(size_t)(brow + r) * DD + d0 + (q << 2)];
            *(float4*)&xs[(r << 6) + (((q ^ (r & 15)) & 15) << 2)] = v;
        }
        // stage ys: 128 rows x 16 quads = 2048 f4 -> 4 each
#pragma unroll
        for (int k = 0; k < 4; ++k) {
            int idx = tid + k * 512;
            int r = idx >> 4, q = idx & 15;
            float4 v = *(const float4*)&Y[(size_t)(bcol + r) * DD + d0 + (q << 2)];
            *(float4*)&ys[(r << 6) + (((q ^ (r & 15)) & 15) << 2)] = v;
        }
        __syncthreads();

#pragma unroll 4
        for (int dq = 0; dq < DK / 4; ++dq) {
            float4 xv[TM], yv[TN];
#pragma unroll
            for (int i = 0; i < TM; ++i) {
                int r = ty + 32 * i;
                xv[i] = *(const float4*)&xs[(r << 6) + (((dq ^ (r & 15)) & 15) << 2)];
            }
#pragma unroll
            for (int j = 0; j < TN; ++j) {
                int c = tx + 16 * j;               // c & 15 == tx
                yv[j] = *(const float4*)&ys[(c << 6) + (((dq ^ tx) & 15) << 2)];
            }
#pragma unroll
            for (int i = 0; i < TM; ++i)
#pragma unroll
                for (int j = 0; j < TN; ++j) {
                    acc[i][j] += __builtin_fabsf(xv[i].x - yv[j].x);
                    acc[i][j] += __builtin_fabsf(xv[i].y - yv[j].y);
                    acc[i][j] += __builtin_fabsf(xv[i].z - yv[j].z);
                    acc[i][j] += __builtin_fabsf(xv[i].w - yv[j].w);
                }
        }
    }

#pragma unroll
    for (int i = 0; i < TM; ++i) {
        int r = brow + ty + 32 * i;
#pragma unroll
        for (int j = 0; j < TN; ++j) {
            int c = bcol + tx + 16 * j;
            out[(size_t)r * M + c] = -acc[i][j];
        }
    }
}

extern "C" void kernel_launch(void* const* d_in, const int* in_sizes, int n_in,
                              void* d_out, int out_size, void* d_ws, size_t ws_size,
                              hipStream_t stream) {
    const float* x = (const float*)d_in[0];
    const float* y = (const float*)d_in[1];
    float* out = (float*)d_out;
    const int D = DD;
    const int N = in_sizes[0] / D;   // 2048
    const int M = in_sizes[1] / D;   // 2048
    dim3 grid(M / BCOLS, N / BROWS); // (16, 32) = 512 blocks
    l1_dist_kernel<<<grid, 512, 0, stream>>>(x, y, out, N, M);
}

// Round 5
// 32.555 us; speedup vs baseline: 2.2680x; 1.3875x over previous
//
#include <hip/hip_runtime.h>

// out[n,m] = -sum_d |x[n,d]-y[m,d]|  N=M=2048, D=128, fp32.  VALU-bound.
// R3 post-mortem: LDS-tiled structure reads 1.34 GB from LDS (~5.2MB/CU,
// 41-62k cyc) -> LDS pipe floors it at ~17-26us. Eliminate LDS entirely:
//  - x rows are wave-uniform -> constant-AS s_load (SMEM pipe, data in
//    SGPRs, v_sub_f32 v,s,v consumes directly). Proven to engage in R2
//    (SGPR_Count=112).
//  - y chunked to 32 floats (8 x float4 = 32 VGPR) per d-chunk -> no
//    spill (R2's failure was yv[32] = 128 VGPR residency).
// Inner (chunk,row): 2x s_load_dwordx16 + 64 VALU (4 indep acc chains).
// 4096 waves = 4/SIMD, no barriers, no LDS.

typedef float f4 __attribute__((ext_vector_type(4)));
typedef __attribute__((address_space(4))) const f4 cf4;

#define DD 128
#define ROWS 16   // rows per wave
#define NCH 4     // d-chunks of 32 floats

__launch_bounds__(256)
__global__ void l1_dist_kernel(const float* __restrict__ X,
                               const float* __restrict__ Y,
                               float* __restrict__ out,
                               int N, int M) {
    const int wave = __builtin_amdgcn_readfirstlane((int)(threadIdx.x >> 6));
    const int lane = threadIdx.x & 63;
    const int gw = blockIdx.x * 4 + wave;   // 0..4095
    const int mg = gw & 31;                 // 32 column groups
    const int rg = gw >> 5;                 // 128 row groups
    const int m  = mg * 64 + lane;
    const int n0 = rg * ROWS;

    float acc[ROWS];
#pragma unroll
    for (int r = 0; r < ROWS; ++r) acc[r] = 0.f;

#pragma unroll
    for (int c = 0; c < NCH; ++c) {
        // This lane's y chunk: 32 floats = 8 float4 = 32 VGPR. L2-hot.
        f4 yv[8];
        const f4* yp = (const f4*)(Y + (size_t)m * DD + c * 32);
#pragma unroll
        for (int k = 0; k < 8; ++k) yv[k] = yp[k];

#pragma unroll
        for (int r = 0; r < ROWS; ++r) {
            // wave-uniform, constant AS -> 2x s_load_dwordx16 on SMEM pipe
            cf4* xp = (cf4*)(X + (size_t)(n0 + r) * DD + c * 32);
            float a0 = 0.f, a1 = 0.f, a2 = 0.f, a3 = 0.f;
#pragma unroll
            for (int k = 0; k < 8; ++k) {
                f4 xv = xp[k];
                a0 += __builtin_fabsf(xv.x - yv[k].x);
                a1 += __builtin_fabsf(xv.y - yv[k].y);
                a2 += __builtin_fabsf(xv.z - yv[k].z);
                a3 += __builtin_fabsf(xv.w - yv[k].w);
            }
            acc[r] += (a0 + a1) + (a2 + a3);
        }
    }

#pragma unroll
    for (int r = 0; r < ROWS; ++r)
        out[(size_t)(n0 + r) * M + m] = -acc[r];   // 256B coalesced/wave
}

extern "C" void kernel_launch(void* const* d_in, const int* in_sizes, int n_in,
                              void* d_out, int out_size, void* d_ws, size_t ws_size,
                              hipStream_t stream) {
    const float* x = (const float*)d_in[0];
    const float* y = (const float*)d_in[1];
    float* out = (float*)d_out;
    const int N = in_sizes[0] / DD;   // 2048
    const int M = in_sizes[1] / DD;   // 2048
    const int waves = (M / 64) * (N / ROWS);  // 4096
    dim3 grid(waves / 4);                     // 1024 blocks of 256 threads
    l1_dist_kernel<<<grid, 256, 0, stream>>>(x, y, out, N, M);
}